// Round 3
// baseline (865.248 us; speedup 1.0000x reference)
//
#include <hip/hip_runtime.h>

#define N_NODES 50000
#define N_EDGES 200000
#define DE 32
#define N_FRAG 10000
#define N_GRAPH 2000
#define BN_SLOTS 32
#define KSTR 296   // LDS stride (fp16 elems) for the 32-row A/h1 plane

typedef _Float16 f16x8 __attribute__((ext_vector_type(8)));
typedef _Float16 f16x4 __attribute__((ext_vector_type(4)));
typedef __attribute__((ext_vector_type(4))) float f32x4;

__device__ __forceinline__ float4 ld4(const float* p) { return *(const float4*)p; }
__device__ __forceinline__ float4 ld4(const _Float16* p) {
    f16x4 h = *(const f16x4*)p;
    float4 v; v.x = (float)h[0]; v.y = (float)h[1]; v.z = (float)h[2]; v.w = (float)h[3];
    return v;
}
__device__ __forceinline__ void st4h(_Float16* p, float4 v) {
    f16x4 h = {(_Float16)v.x, (_Float16)v.y, (_Float16)v.z, (_Float16)v.w};
    *(f16x4*)p = h;
}

// ---------------------------------------------------------------------------
// CSR build: in-degree count, hierarchical scan, fill
__global__ __launch_bounds__(256)
void count_deg_kernel(const int* __restrict__ ei, int* __restrict__ deg) {
    int e = blockIdx.x * 256 + threadIdx.x;
    if (e < N_EDGES) atomicAdd(&deg[ei[N_EDGES + e]], 1);
}

__global__ __launch_bounds__(256)
void block_sum_kernel(const int* __restrict__ deg, int* __restrict__ bsum) {
    int i = blockIdx.x * 256 + threadIdx.x;
    int v = (i < N_NODES) ? deg[i] : 0;
#pragma unroll
    for (int o = 1; o < 64; o <<= 1) v += __shfl_xor(v, o);
    __shared__ int wsum[4];
    if ((threadIdx.x & 63) == 0) wsum[threadIdx.x >> 6] = v;
    __syncthreads();
    if (threadIdx.x == 0) bsum[blockIdx.x] = wsum[0] + wsum[1] + wsum[2] + wsum[3];
}

__global__ __launch_bounds__(256)
void top_scan_kernel(int* __restrict__ bsum, int nb) {
    __shared__ int s[256];
    int t = threadIdx.x;
    s[t] = (t < nb) ? bsum[t] : 0;
    __syncthreads();
    for (int o = 1; o < 256; o <<= 1) {
        int v = s[t];
        int a = (t >= o) ? s[t - o] : 0;
        __syncthreads();
        s[t] = v + a;
        __syncthreads();
    }
    if (t < nb) bsum[t] = (t > 0) ? s[t - 1] : 0;
}

__global__ __launch_bounds__(256)
void final_scan_kernel(const int* __restrict__ deg, const int* __restrict__ bsum,
                       int* __restrict__ ptr) {
    __shared__ int s[256];
    int i = blockIdx.x * 256 + threadIdx.x;
    int t = threadIdx.x;
    int v = (i < N_NODES) ? deg[i] : 0;
    s[t] = v;
    __syncthreads();
    for (int o = 1; o < 256; o <<= 1) {
        int x = s[t];
        int a = (t >= o) ? s[t - o] : 0;
        __syncthreads();
        s[t] = x + a;
        __syncthreads();
    }
    int incl = s[t];
    int base = bsum[blockIdx.x];
    if (i < N_NODES) ptr[i] = base + incl - v;
    if (i == N_NODES - 1) ptr[N_NODES] = base + incl;
}

__global__ __launch_bounds__(256)
void fill_csr_kernel(const int* __restrict__ ei, const int* __restrict__ row_ptr,
                     int* __restrict__ fill, int* __restrict__ csr_src,
                     int* __restrict__ csr_eid) {
    int e = blockIdx.x * 256 + threadIdx.x;
    if (e >= N_EDGES) return;
    int dst = ei[N_EDGES + e];
    int pos = row_ptr[dst] + atomicAdd(&fill[dst], 1);
    csr_src[pos] = ei[e];
    csr_eid[pos] = e;
}

__global__ __launch_bounds__(256)
void segptr_kernel(const int* __restrict__ batch, int nseg, int* __restrict__ ptr) {
    int s = blockIdx.x * 256 + threadIdx.x;
    if (s > nseg) return;
    int lo = 0, hi = N_NODES;
    while (lo < hi) {
        int mid = (lo + hi) >> 1;
        if (batch[mid] < s) lo = mid + 1; else hi = mid;
    }
    ptr[s] = lo;
}

// ---------------------------------------------------------------------------
// Degree-sorted permutation (counting sort, 64 bins): load-balances the
// gather stage so every 32-row block has ~uniform degree.
__global__ __launch_bounds__(256)
void deg_hist_kernel(const int* __restrict__ deg, int* __restrict__ hist) {
    int i = blockIdx.x * 256 + threadIdx.x;
    if (i < N_NODES) atomicAdd(&hist[min(deg[i], 63)], 1);
}

__global__ void binscan_kernel(int* __restrict__ hist, int* __restrict__ perm) {
    __shared__ int s[64];
    int t = threadIdx.x;   // 64 threads
    s[t] = hist[t];
    __syncthreads();
    for (int o = 1; o < 64; o <<= 1) {
        int v = s[t];
        int a = (t >= o) ? s[t - o] : 0;
        __syncthreads();
        s[t] = v + a;
        __syncthreads();
    }
    hist[t] = (t > 0) ? s[t - 1] : 0;   // exclusive base
    if (t < 16) perm[N_NODES + t] = -1; // pad to 1563*32
}

__global__ __launch_bounds__(256)
void scatter_perm_kernel(const int* __restrict__ deg, const int* __restrict__ base,
                         int* __restrict__ fill64, int* __restrict__ perm) {
    int i = blockIdx.x * 256 + threadIdx.x;
    if (i >= N_NODES) return;
    int b = min(deg[i], 63);
    int pos = base[b] + atomicAdd(&fill64[b], 1);
    perm[pos] = i;
}

// ---------------------------------------------------------------------------
// W [K][256] fp32 -> fragment-swizzled fp16 BS:
// BS[kt][cg][lane][j] = fp16(W[kt*32 + (lane>>4)*8 + j][cg*16 + (lane&15)])
__global__ __launch_bounds__(256)
void bs16_kernel(const float* __restrict__ W, _Float16* __restrict__ BS, int K) {
    int id = blockIdx.x * 256 + threadIdx.x;
    if (id >= K * 256) return;
    int j  = id & 7;
    int l  = (id >> 3) & 63;
    int cg = (id >> 9) & 15;
    int kt = id >> 13;
    int col = cg * 16 + (l & 15);
    int k   = kt * 32 + (l >> 4) * 8 + j;
    BS[id] = (_Float16)W[(size_t)k * 256 + col];
}

// ---------------------------------------------------------------------------
// agg_e[n] = sum over incoming edges of relu(edge_attr[e])  [N,32]
__global__ __launch_bounds__(256)
void edge_gather_kernel(const float* __restrict__ ea, const int* __restrict__ row_ptr,
                        const int* __restrict__ csr_eid, float* __restrict__ agg_e) {
    int t = threadIdx.x;
    int g = t >> 3;
    int j = t & 7;
    int n = blockIdx.x * 32 + g;
    if (n >= N_NODES) return;
    int col = j << 2;
    float4 acc = {0.f, 0.f, 0.f, 0.f};
    int beg = row_ptr[n], end = row_ptr[n + 1];
    for (int e = beg; e < end; ++e) {
        int eid = csr_eid[e];
        float4 v = *(const float4*)(ea + (size_t)eid * DE + col);
        acc.x += fmaxf(v.x, 0.f);
        acc.y += fmaxf(v.y, 0.f);
        acc.z += fmaxf(v.z, 0.f);
        acc.w += fmaxf(v.w, 0.f);
    }
    *(float4*)(agg_e + (size_t)n * DE + col) = acc;
}

// ---------------------------------------------------------------------------
// Pre-activation buffers for the gather: Y0 = fp16(relu(x)) (layer 0),
// Y = fp16(relu(sc*h+sh)) (layers 1,2). Gather loop then is pure fp16 adds.
__global__ __launch_bounds__(256)
void relu16_f32_kernel(const float* __restrict__ x, _Float16* __restrict__ y) {
    size_t i = (size_t)(blockIdx.x * 256 + threadIdx.x) * 4;   // N*128 total
    if (i >= (size_t)N_NODES * 128) return;
    float4 v = ld4(x + i);
    f16x4 o = {(_Float16)fmaxf(v.x, 0.f), (_Float16)fmaxf(v.y, 0.f),
               (_Float16)fmaxf(v.z, 0.f), (_Float16)fmaxf(v.w, 0.f)};
    *(f16x4*)(y + i) = o;
}

__global__ __launch_bounds__(256)
void bnrelu16_kernel(const _Float16* __restrict__ h, const float* __restrict__ sc,
                     const float* __restrict__ sh, _Float16* __restrict__ y) {
    size_t i = (size_t)(blockIdx.x * 256 + threadIdx.x) * 8;   // N*256 total
    if (i >= (size_t)N_NODES * 256) return;
    int col = (int)(i & 255);
    f16x8 v = *(const f16x8*)(h + i);
    float4 s0 = ld4(sc + col), s1 = ld4(sc + col + 4);
    float4 t0 = ld4(sh + col), t1 = ld4(sh + col + 4);
    f16x8 o;
    o[0] = (_Float16)fmaxf(fmaf((float)v[0], s0.x, t0.x), 0.f);
    o[1] = (_Float16)fmaxf(fmaf((float)v[1], s0.y, t0.y), 0.f);
    o[2] = (_Float16)fmaxf(fmaf((float)v[2], s0.z, t0.z), 0.f);
    o[3] = (_Float16)fmaxf(fmaf((float)v[3], s0.w, t0.w), 0.f);
    o[4] = (_Float16)fmaxf(fmaf((float)v[4], s1.x, t1.x), 0.f);
    o[5] = (_Float16)fmaxf(fmaf((float)v[5], s1.y, t1.y), 0.f);
    o[6] = (_Float16)fmaxf(fmaf((float)v[6], s1.z, t1.z), 0.f);
    o[7] = (_Float16)fmaxf(fmaf((float)v[7], s1.w, t1.w), 0.f);
    *(f16x8*)(y + i) = o;
}

// ---------------------------------------------------------------------------
// Fused gather + MLP (degree-sorted rows):
//   stage: agg row = self(BN) + sum_{e} Y[src] || agg_e[n], fp32 accum,
//          depth-2 pipelined 16B loads; rows via perm[] (uniform degree/block).
//   then:  xout = fp16(relu( relu(A@W1+b1) @ W2 + b2 )), + BN stats.
// 32 rows/block, 4 waves each own a 64-col slab; ~19KB LDS.
template <bool BNIN, typename T, int NC>   // DIN = NC*32, K1 = DIN+32
__global__ __launch_bounds__(256)
void fused_mlp_kernel(const T* __restrict__ X, const _Float16* __restrict__ Yg,
                      const int* __restrict__ perm,
                      const int* __restrict__ row_ptr, const int* __restrict__ csr_src,
                      const float* __restrict__ agg_e,
                      const float* __restrict__ bnsc, const float* __restrict__ bnsh,
                      const _Float16* __restrict__ B1, const float* __restrict__ bias1,
                      const _Float16* __restrict__ B2, const float* __restrict__ bias2,
                      _Float16* __restrict__ C, float* __restrict__ bnslot) {
    constexpr int DIN  = NC * 32;
    constexpr int K1   = DIN + 32;
    constexpr int NKT1 = K1 / 32;
    constexpr int CPT  = DIN / 8;        // cols per stage-thread
    constexpr int NV   = CPT / 8;        // f16x8 loads per neighbor
    __shared__ __align__(16) _Float16 sBuf[32 * KSTR];   // A tile, then h1
    __shared__ int sPerm[32];
    const int t = threadIdx.x;
    const int l = t & 63;
    const int w = t >> 6;
    const int lr = l & 15;
    const int lq = l >> 4;
    const int cb = w << 6;

    if (t < 32) sPerm[t] = perm[(blockIdx.x << 5) + t];
    __syncthreads();

    // ---- stage: gather-aggregate directly into LDS (8 threads/row) ----
    {
        const int r = t >> 3, j = t & 7;
        const int gr = sPerm[r];
        if (gr >= 0) {
            float accf[CPT];
#pragma unroll
            for (int c = 0; c < CPT; ++c) accf[c] = 0.f;
            const int beg = row_ptr[gr], end = row_ptr[gr + 1];
            // depth-2 pipelined neighbor loop: pure fp16 adds (relu/BN in Yg)
            int e = beg;
            f16x8 v0[NV];
            if (e < end) {
                const _Float16* sp = Yg + (size_t)csr_src[e] * DIN + j * CPT;
#pragma unroll
                for (int c = 0; c < NV; ++c) v0[c] = *(const f16x8*)(sp + c * 8);
            }
            for (; e < end; ++e) {
                f16x8 v1[NV];
                if (e + 1 < end) {
                    const _Float16* sp = Yg + (size_t)csr_src[e + 1] * DIN + j * CPT;
#pragma unroll
                    for (int c = 0; c < NV; ++c) v1[c] = *(const f16x8*)(sp + c * 8);
                }
#pragma unroll
                for (int c = 0; c < NV; ++c)
#pragma unroll
                    for (int k = 0; k < 8; ++k) accf[c * 8 + k] += (float)v0[c][k];
#pragma unroll
                for (int c = 0; c < NV; ++c) v0[c] = v1[c];
            }
            // self term (BN if BNIN, no relu)
            const T* xp = X + (size_t)gr * DIN + j * CPT;
#pragma unroll
            for (int c2 = 0; c2 < CPT / 4; ++c2) {
                float4 v = ld4(xp + c2 * 4);
                if (BNIN) {
                    float4 sc4 = *(const float4*)(bnsc + j * CPT + c2 * 4);
                    float4 sh4 = *(const float4*)(bnsh + j * CPT + c2 * 4);
                    v.x = fmaf(v.x, sc4.x, sh4.x);
                    v.y = fmaf(v.y, sc4.y, sh4.y);
                    v.z = fmaf(v.z, sc4.z, sh4.z);
                    v.w = fmaf(v.w, sc4.w, sh4.w);
                }
                accf[c2 * 4 + 0] += v.x;
                accf[c2 * 4 + 1] += v.y;
                accf[c2 * 4 + 2] += v.z;
                accf[c2 * 4 + 3] += v.w;
            }
            // store fp16 row to LDS
#pragma unroll
            for (int c = 0; c < NV; ++c) {
                f16x8 o;
#pragma unroll
                for (int k = 0; k < 8; ++k) o[k] = (_Float16)accf[c * 8 + k];
                *(f16x8*)&sBuf[r * KSTR + j * CPT + c * 8] = o;
            }
            float4 ev = *(const float4*)(agg_e + (size_t)gr * DE + (j << 2));
            st4h(&sBuf[r * KSTR + DIN + (j << 2)], ev);
        } else {
            f16x8 z8 = {0, 0, 0, 0, 0, 0, 0, 0};
#pragma unroll
            for (int c = 0; c < NV; ++c)
                *(f16x8*)&sBuf[r * KSTR + j * CPT + c * 8] = z8;
            f16x4 z4 = {0, 0, 0, 0};
            *(f16x4*)&sBuf[r * KSTR + DIN + (j << 2)] = z4;
        }
    }
    __syncthreads();

    // ---- phase 1: A @ W1 (barrier-free) ----
    f32x4 acc1[2][4];
#pragma unroll
    for (int mt = 0; mt < 2; ++mt)
#pragma unroll
        for (int nt = 0; nt < 4; ++nt) acc1[mt][nt] = (f32x4){0.f, 0.f, 0.f, 0.f};
#pragma unroll
    for (int kt = 0; kt < NKT1; ++kt) {
        f16x8 af[2], bf[4];
#pragma unroll
        for (int mt = 0; mt < 2; ++mt)
            af[mt] = *(const f16x8*)&sBuf[(mt * 16 + lr) * KSTR + (kt << 5) + (lq << 3)];
        const size_t bb = ((size_t)(kt * 16 + (w << 2))) * 512 + (l << 3);
#pragma unroll
        for (int nt = 0; nt < 4; ++nt)
            bf[nt] = *(const f16x8*)(B1 + bb + nt * 512);
#pragma unroll
        for (int mt = 0; mt < 2; ++mt)
#pragma unroll
            for (int nt = 0; nt < 4; ++nt)
                acc1[mt][nt] = __builtin_amdgcn_mfma_f32_16x16x32_f16(
                    af[mt], bf[nt], acc1[mt][nt], 0, 0, 0);
    }
    __syncthreads();   // A tile dead; reuse plane for h1

    // ---- epilogue 1: relu(h1) -> LDS fp16 ----
#pragma unroll
    for (int nt = 0; nt < 4; ++nt) {
        int col = cb + nt * 16 + lr;
        float bv = bias1[col];
#pragma unroll
        for (int mt = 0; mt < 2; ++mt)
#pragma unroll
            for (int i = 0; i < 4; ++i) {
                int rr = mt * 16 + lq * 4 + i;
                sBuf[rr * KSTR + col] = (_Float16)fmaxf(acc1[mt][nt][i] + bv, 0.f);
            }
    }
    __syncthreads();

    // ---- phase 2: h1 @ W2 (barrier-free) ----
    f32x4 acc2[2][4];
#pragma unroll
    for (int mt = 0; mt < 2; ++mt)
#pragma unroll
        for (int nt = 0; nt < 4; ++nt) acc2[mt][nt] = (f32x4){0.f, 0.f, 0.f, 0.f};
#pragma unroll
    for (int kt = 0; kt < 8; ++kt) {
        f16x8 af[2], bf[4];
#pragma unroll
        for (int mt = 0; mt < 2; ++mt)
            af[mt] = *(const f16x8*)&sBuf[(mt * 16 + lr) * KSTR + (kt << 5) + (lq << 3)];
        const size_t bb = ((size_t)(kt * 16 + (w << 2))) * 512 + (l << 3);
#pragma unroll
        for (int nt = 0; nt < 4; ++nt)
            bf[nt] = *(const f16x8*)(B2 + bb + nt * 512);
#pragma unroll
        for (int mt = 0; mt < 2; ++mt)
#pragma unroll
            for (int nt = 0; nt < 4; ++nt)
                acc2[mt][nt] = __builtin_amdgcn_mfma_f32_16x16x32_f16(
                    af[mt], bf[nt], acc2[mt][nt], 0, 0, 0);
    }

    // ---- epilogue 2: bias + relu + fp16 store + BN stats ----
    float* slot = bnslot + (size_t)(blockIdx.x & (BN_SLOTS - 1)) * 512;
#pragma unroll
    for (int nt = 0; nt < 4; ++nt) {
        int col = cb + nt * 16 + lr;
        float bv = bias2[col];
        float s = 0.f, qq = 0.f;
#pragma unroll
        for (int mt = 0; mt < 2; ++mt)
#pragma unroll
            for (int i = 0; i < 4; ++i) {
                int row = sPerm[mt * 16 + lq * 4 + i];
                if (row >= 0) {
                    float o = fmaxf(acc2[mt][nt][i] + bv, 0.f);
                    C[(size_t)row * 256 + col] = (_Float16)o;
                    s += o; qq += o * o;
                }
            }
        s += __shfl_xor(s, 16); s += __shfl_xor(s, 32);
        qq += __shfl_xor(qq, 16); qq += __shfl_xor(qq, 32);
        if (lq == 0) {
            atomicAdd(&slot[col], s);
            atomicAdd(&slot[256 + col], qq);
        }
    }
}

// reduce BN_SLOTS slots -> scale/shift
__global__ void bn_finalize_kernel(const float* __restrict__ slots,
                                   const float* __restrict__ g, const float* __restrict__ beta,
                                   float* __restrict__ scale, float* __restrict__ shift) {
    int c = threadIdx.x;
    float s = 0.f, q = 0.f;
    for (int k = 0; k < BN_SLOTS; ++k) {
        s += slots[(size_t)k * 512 + c];
        q += slots[(size_t)k * 512 + 256 + c];
    }
    float mu = s * (1.0f / N_NODES);
    float var = q * (1.0f / N_NODES) - mu * mu;
    float rstd = rsqrtf(var + 1e-5f);
    float sc = g[c] * rstd;
    scale[c] = sc;
    shift[c] = beta[c] - mu * sc;
}

// segmented sqrt-pool (fp16 input) with BN applied at load; fp32 output
__global__ __launch_bounds__(256)
void pool_seg_kernel(const _Float16* __restrict__ h, const int* __restrict__ ptr,
                     const float* __restrict__ bnsc, const float* __restrict__ bnsh,
                     float* __restrict__ out, int nseg) {
    int t = threadIdx.x;
    int g = t >> 6;
    int j = t & 63;
    int s = blockIdx.x * 4 + g;
    if (s >= nseg) return;
    int beg = ptr[s], end = ptr[s + 1];
    int col = j << 2;
    float4 sc = *(const float4*)(bnsc + col);
    float4 sh = *(const float4*)(bnsh + col);
    float4 acc = {0.f, 0.f, 0.f, 0.f};
    for (int i = beg; i < end; ++i) {
        float4 v = ld4(h + (size_t)i * 256 + col);
        acc.x += fmaf(v.x, sc.x, sh.x);
        acc.y += fmaf(v.y, sc.y, sh.y);
        acc.z += fmaf(v.z, sc.z, sh.z);
        acc.w += fmaf(v.w, sc.w, sh.w);
    }
    float w = rsqrtf(fmaxf((float)(end - beg), 1.0f));
    float4 o = {acc.x * w, acc.y * w, acc.z * w, acc.w * w};
    *(float4*)(out + (size_t)s * 256 + col) = o;
}

// ---------------------------------------------------------------------------
extern "C" void kernel_launch(void* const* d_in, const int* in_sizes, int n_in,
                              void* d_out, int out_size, void* d_ws, size_t ws_size,
                              hipStream_t stream) {
    const float* x  = (const float*)d_in[0];
    const float* ea = (const float*)d_in[1];
    const int*   ei = (const int*)d_in[2];
    const int*   fb = (const int*)d_in[3];
    const int*   gb = (const int*)d_in[4];
    const float* W1[3]   = {(const float*)d_in[5],  (const float*)d_in[11], (const float*)d_in[17]};
    const float* B1[3]   = {(const float*)d_in[6],  (const float*)d_in[12], (const float*)d_in[18]};
    const float* W2[3]   = {(const float*)d_in[7],  (const float*)d_in[13], (const float*)d_in[19]};
    const float* B2[3]   = {(const float*)d_in[8],  (const float*)d_in[14], (const float*)d_in[20]};
    const float* G[3]    = {(const float*)d_in[9],  (const float*)d_in[15], (const float*)d_in[21]};
    const float* BETA[3] = {(const float*)d_in[10], (const float*)d_in[16], (const float*)d_in[22]};

    const int FIN[3] = {160, 288, 288};
    const int NBLK = (N_NODES + 255) / 256;      // scan blocks

    float* ws = (float*)d_ws;
    size_t off = 0;
    _Float16* bufA = (_Float16*)(ws + off); off += (size_t)N_NODES * 128;  // N x 256 fp16
    _Float16* bufB = (_Float16*)(ws + off); off += (size_t)N_NODES * 128;
    _Float16* ybuf = (_Float16*)(ws + off); off += (size_t)N_NODES * 128;  // pre-activation Y
    float* agg_e = ws + off; off += (size_t)N_NODES * DE;
    float* bnss  = ws + off; off += 3 * 512;                 // per layer: scale|shift
    float* bnslots = ws + off; off += (size_t)3 * BN_SLOTS * 512;
    _Float16* w1f[3]; _Float16* w2f[3];
    {
        _Float16* sw = (_Float16*)(ws + off);
        _Float16* sw0 = sw;
        for (int l = 0; l < 3; ++l) { w1f[l] = sw; sw += 256 * FIN[l]; }
        for (int l = 0; l < 3; ++l) { w2f[l] = sw; sw += 256 * 256; }
        off += (size_t)(sw - sw0 + 1) / 2;
    }
    int* iw      = (int*)(ws + off);
    int* row_ptr = iw;                     iw += N_NODES + 1;
    int* deg     = iw;                     iw += N_NODES;
    int* fill    = iw;                     iw += N_NODES;
    int* csr_src = iw;                     iw += N_EDGES;
    int* csr_eid = iw;                     iw += N_EDGES;
    int* frag_ptr = iw;                    iw += N_FRAG + 1;
    int* graph_ptr = iw;                   iw += N_GRAPH + 1;
    int* bsum    = iw;                     iw += NBLK;
    int* perm    = iw;                     iw += N_NODES + 16;
    int* hist    = iw;                     iw += 64;
    int* fill64  = iw;                     iw += 64;

    hipMemsetAsync(deg, 0, 2 * N_NODES * sizeof(int), stream);
    hipMemsetAsync(hist, 0, 128 * sizeof(int), stream);
    hipMemsetAsync(bnslots, 0, (size_t)3 * BN_SLOTS * 512 * sizeof(float), stream);

    // weight fragment-swizzle to fp16 (once per layer)
    for (int l = 0; l < 3; ++l) {
        bs16_kernel<<<(FIN[l] * 256 + 255) / 256, 256, 0, stream>>>(W1[l], w1f[l], FIN[l]);
        bs16_kernel<<<(256 * 256 + 255) / 256, 256, 0, stream>>>(W2[l], w2f[l], 256);
    }

    // CSR build (hierarchical scan)
    count_deg_kernel<<<(N_EDGES + 255) / 256, 256, 0, stream>>>(ei, deg);
    block_sum_kernel<<<NBLK, 256, 0, stream>>>(deg, bsum);
    top_scan_kernel<<<1, 256, 0, stream>>>(bsum, NBLK);
    final_scan_kernel<<<NBLK, 256, 0, stream>>>(deg, bsum, row_ptr);
    fill_csr_kernel<<<(N_EDGES + 255) / 256, 256, 0, stream>>>(ei, row_ptr, fill, csr_src, csr_eid);

    // degree-sorted permutation
    deg_hist_kernel<<<NBLK, 256, 0, stream>>>(deg, hist);
    binscan_kernel<<<1, 64, 0, stream>>>(hist, perm);
    scatter_perm_kernel<<<NBLK, 256, 0, stream>>>(deg, hist, fill64, perm);

    segptr_kernel<<<(N_FRAG + 1 + 255) / 256, 256, 0, stream>>>(fb, N_FRAG, frag_ptr);
    segptr_kernel<<<(N_GRAPH + 1 + 255) / 256, 256, 0, stream>>>(gb, N_GRAPH, graph_ptr);

    edge_gather_kernel<<<(N_NODES + 31) / 32, 256, 0, stream>>>(ea, row_ptr, csr_eid, agg_e);

    const int nblk_mlp = (N_NODES + 31) / 32;    // 1563 blocks, 32 rows each
    // layer 0: Y0 = fp16(relu(x)), self = x (fp32)
    relu16_f32_kernel<<<(N_NODES * 128 / 4 + 255) / 256, 256, 0, stream>>>(x, ybuf);
    {
        float* slotsL = bnslots;
        fused_mlp_kernel<false, float, 4><<<nblk_mlp, 256, 0, stream>>>(
            x, ybuf, perm, row_ptr, csr_src, agg_e, nullptr, nullptr,
            w1f[0], B1[0], w2f[0], B2[0], bufA, slotsL);
        bn_finalize_kernel<<<1, 256, 0, stream>>>(slotsL, G[0], BETA[0], bnss, bnss + 256);
    }
    // layer 1: Y = fp16(relu(BN0(bufA))), self = BN0(bufA)
    {
        float* slotsL = bnslots + (size_t)1 * BN_SLOTS * 512;
        const float* psc = bnss, * psh = bnss + 256;
        bnrelu16_kernel<<<(N_NODES * 256 / 8 + 255) / 256, 256, 0, stream>>>(bufA, psc, psh, ybuf);
        fused_mlp_kernel<true, _Float16, 8><<<nblk_mlp, 256, 0, stream>>>(
            bufA, ybuf, perm, row_ptr, csr_src, agg_e, psc, psh,
            w1f[1], B1[1], w2f[1], B2[1], bufB, slotsL);
        bn_finalize_kernel<<<1, 256, 0, stream>>>(slotsL, G[1], BETA[1], bnss + 512, bnss + 768);
    }
    // layer 2: Y = fp16(relu(BN1(bufB))), self = BN1(bufB)
    {
        float* slotsL = bnslots + (size_t)2 * BN_SLOTS * 512;
        const float* psc = bnss + 512, * psh = bnss + 768;
        bnrelu16_kernel<<<(N_NODES * 256 / 8 + 255) / 256, 256, 0, stream>>>(bufB, psc, psh, ybuf);
        fused_mlp_kernel<true, _Float16, 8><<<nblk_mlp, 256, 0, stream>>>(
            bufB, ybuf, perm, row_ptr, csr_src, agg_e, psc, psh,
            w1f[2], B1[2], w2f[2], B2[2], bufA, slotsL);
        bn_finalize_kernel<<<1, 256, 0, stream>>>(slotsL, G[2], BETA[2], bnss + 1024, bnss + 1280);
    }

    const float* fsc = bnss + 2 * 512;   // layer-2 BN scale/shift
    const float* fsh = fsc + 256;
    pool_seg_kernel<<<(N_FRAG + 3) / 4, 256, 0, stream>>>(bufA, frag_ptr, fsc, fsh,
                                                          (float*)d_out, N_FRAG);
    pool_seg_kernel<<<(N_GRAPH + 3) / 4, 256, 0, stream>>>(bufA, graph_ptr, fsc, fsh,
                                                           (float*)d_out + (size_t)N_FRAG * 256, N_GRAPH);
}

// Round 4
// 456.530 us; speedup vs baseline: 1.8953x; 1.8953x over previous
//
#include <hip/hip_runtime.h>

#define N_NODES 50000
#define N_EDGES 200000
#define DE 32
#define N_FRAG 10000
#define N_GRAPH 2000
#define BN_SLOTS 32
#define KSTR 296   // LDS stride (fp16 elems) for the 32-row A/h1 plane

typedef _Float16 f16x8 __attribute__((ext_vector_type(8)));
typedef _Float16 f16x4 __attribute__((ext_vector_type(4)));
typedef __attribute__((ext_vector_type(4))) float f32x4;

__device__ __forceinline__ float4 ld4(const float* p) { return *(const float4*)p; }
__device__ __forceinline__ float4 ld4(const _Float16* p) {
    f16x4 h = *(const f16x4*)p;
    float4 v; v.x = (float)h[0]; v.y = (float)h[1]; v.z = (float)h[2]; v.w = (float)h[3];
    return v;
}
__device__ __forceinline__ void st4h(_Float16* p, float4 v) {
    f16x4 h = {(_Float16)v.x, (_Float16)v.y, (_Float16)v.z, (_Float16)v.w};
    *(f16x4*)p = h;
}

// ---------------------------------------------------------------------------
// CSR build: in-degree count, hierarchical scan, fill
__global__ __launch_bounds__(256)
void count_deg_kernel(const int* __restrict__ ei, int* __restrict__ deg) {
    int e = blockIdx.x * 256 + threadIdx.x;
    if (e < N_EDGES) atomicAdd(&deg[ei[N_EDGES + e]], 1);
}

__global__ __launch_bounds__(256)
void block_sum_kernel(const int* __restrict__ deg, int* __restrict__ bsum) {
    int i = blockIdx.x * 256 + threadIdx.x;
    int v = (i < N_NODES) ? deg[i] : 0;
#pragma unroll
    for (int o = 1; o < 64; o <<= 1) v += __shfl_xor(v, o);
    __shared__ int wsum[4];
    if ((threadIdx.x & 63) == 0) wsum[threadIdx.x >> 6] = v;
    __syncthreads();
    if (threadIdx.x == 0) bsum[blockIdx.x] = wsum[0] + wsum[1] + wsum[2] + wsum[3];
}

__global__ __launch_bounds__(256)
void top_scan_kernel(int* __restrict__ bsum, int nb) {
    __shared__ int s[256];
    int t = threadIdx.x;
    s[t] = (t < nb) ? bsum[t] : 0;
    __syncthreads();
    for (int o = 1; o < 256; o <<= 1) {
        int v = s[t];
        int a = (t >= o) ? s[t - o] : 0;
        __syncthreads();
        s[t] = v + a;
        __syncthreads();
    }
    if (t < nb) bsum[t] = (t > 0) ? s[t - 1] : 0;
}

__global__ __launch_bounds__(256)
void final_scan_kernel(const int* __restrict__ deg, const int* __restrict__ bsum,
                       int* __restrict__ ptr) {
    __shared__ int s[256];
    int i = blockIdx.x * 256 + threadIdx.x;
    int t = threadIdx.x;
    int v = (i < N_NODES) ? deg[i] : 0;
    s[t] = v;
    __syncthreads();
    for (int o = 1; o < 256; o <<= 1) {
        int x = s[t];
        int a = (t >= o) ? s[t - o] : 0;
        __syncthreads();
        s[t] = x + a;
        __syncthreads();
    }
    int incl = s[t];
    int base = bsum[blockIdx.x];
    if (i < N_NODES) ptr[i] = base + incl - v;
    if (i == N_NODES - 1) ptr[N_NODES] = base + incl;
}

__global__ __launch_bounds__(256)
void fill_csr_kernel(const int* __restrict__ ei, const int* __restrict__ row_ptr,
                     int* __restrict__ fill, int* __restrict__ csr_src,
                     int* __restrict__ csr_eid) {
    int e = blockIdx.x * 256 + threadIdx.x;
    if (e >= N_EDGES) return;
    int dst = ei[N_EDGES + e];
    int pos = row_ptr[dst] + atomicAdd(&fill[dst], 1);
    csr_src[pos] = ei[e];
    csr_eid[pos] = e;
}

__global__ __launch_bounds__(256)
void segptr_kernel(const int* __restrict__ batch, int nseg, int* __restrict__ ptr) {
    int s = blockIdx.x * 256 + threadIdx.x;
    if (s > nseg) return;
    int lo = 0, hi = N_NODES;
    while (lo < hi) {
        int mid = (lo + hi) >> 1;
        if (batch[mid] < s) lo = mid + 1; else hi = mid;
    }
    ptr[s] = lo;
}

// ---------------------------------------------------------------------------
// Degree-sorted permutation (counting sort, 64 bins): load-balances the
// gather stage so every 32-row block has ~uniform degree.
// LDS-aggregated histograms: the naive versions did 50k device-scope
// atomics onto 64 hot addresses (~200us each from same-address
// serialization). Per-block LDS aggregation cuts global atomics to
// 64/block (~12.5k spread over 64 bins).
__global__ __launch_bounds__(256)
void deg_hist_kernel(const int* __restrict__ deg, int* __restrict__ hist) {
    __shared__ int lh[64];
    int t = threadIdx.x;
    if (t < 64) lh[t] = 0;
    __syncthreads();
    int i = blockIdx.x * 256 + t;
    if (i < N_NODES) atomicAdd(&lh[min(deg[i], 63)], 1);
    __syncthreads();
    if (t < 64 && lh[t]) atomicAdd(&hist[t], lh[t]);
}

__global__ void binscan_kernel(int* __restrict__ hist, int* __restrict__ perm) {
    __shared__ int s[64];
    int t = threadIdx.x;   // 64 threads
    s[t] = hist[t];
    __syncthreads();
    for (int o = 1; o < 64; o <<= 1) {
        int v = s[t];
        int a = (t >= o) ? s[t - o] : 0;
        __syncthreads();
        s[t] = v + a;
        __syncthreads();
    }
    hist[t] = (t > 0) ? s[t - 1] : 0;   // exclusive base
    if (t < 16) perm[N_NODES + t] = -1; // pad to 1563*32
}

__global__ __launch_bounds__(256)
void scatter_perm_kernel(const int* __restrict__ deg, const int* __restrict__ base,
                         int* __restrict__ fill64, int* __restrict__ perm) {
    __shared__ int lh[64];      // local counts / ranks
    __shared__ int lbase[64];   // this block's reserved global base per bin
    int t = threadIdx.x;
    if (t < 64) lh[t] = 0;
    __syncthreads();
    int i = blockIdx.x * 256 + t;
    int b = 0, rank = 0;
    bool ok = (i < N_NODES);
    if (ok) {
        b = min(deg[i], 63);
        rank = atomicAdd(&lh[b], 1);     // LDS atomic: local rank within bin
    }
    __syncthreads();
    if (t < 64 && lh[t]) lbase[t] = atomicAdd(&fill64[t], lh[t]);  // reserve range
    __syncthreads();
    if (ok) perm[base[b] + lbase[b] + rank] = i;
}

// ---------------------------------------------------------------------------
// W [K][256] fp32 -> fragment-swizzled fp16 BS:
// BS[kt][cg][lane][j] = fp16(W[kt*32 + (lane>>4)*8 + j][cg*16 + (lane&15)])
__global__ __launch_bounds__(256)
void bs16_kernel(const float* __restrict__ W, _Float16* __restrict__ BS, int K) {
    int id = blockIdx.x * 256 + threadIdx.x;
    if (id >= K * 256) return;
    int j  = id & 7;
    int l  = (id >> 3) & 63;
    int cg = (id >> 9) & 15;
    int kt = id >> 13;
    int col = cg * 16 + (l & 15);
    int k   = kt * 32 + (l >> 4) * 8 + j;
    BS[id] = (_Float16)W[(size_t)k * 256 + col];
}

// ---------------------------------------------------------------------------
// agg_e[n] = sum over incoming edges of relu(edge_attr[e])  [N,32]
__global__ __launch_bounds__(256)
void edge_gather_kernel(const float* __restrict__ ea, const int* __restrict__ row_ptr,
                        const int* __restrict__ csr_eid, float* __restrict__ agg_e) {
    int t = threadIdx.x;
    int g = t >> 3;
    int j = t & 7;
    int n = blockIdx.x * 32 + g;
    if (n >= N_NODES) return;
    int col = j << 2;
    float4 acc = {0.f, 0.f, 0.f, 0.f};
    int beg = row_ptr[n], end = row_ptr[n + 1];
    for (int e = beg; e < end; ++e) {
        int eid = csr_eid[e];
        float4 v = *(const float4*)(ea + (size_t)eid * DE + col);
        acc.x += fmaxf(v.x, 0.f);
        acc.y += fmaxf(v.y, 0.f);
        acc.z += fmaxf(v.z, 0.f);
        acc.w += fmaxf(v.w, 0.f);
    }
    *(float4*)(agg_e + (size_t)n * DE + col) = acc;
}

// ---------------------------------------------------------------------------
// Pre-activation buffers for the gather: Y0 = fp16(relu(x)) (layer 0),
// Y = fp16(relu(sc*h+sh)) (layers 1,2). Gather loop then is pure fp16 adds.
__global__ __launch_bounds__(256)
void relu16_f32_kernel(const float* __restrict__ x, _Float16* __restrict__ y) {
    size_t i = (size_t)(blockIdx.x * 256 + threadIdx.x) * 4;   // N*128 total
    if (i >= (size_t)N_NODES * 128) return;
    float4 v = ld4(x + i);
    f16x4 o = {(_Float16)fmaxf(v.x, 0.f), (_Float16)fmaxf(v.y, 0.f),
               (_Float16)fmaxf(v.z, 0.f), (_Float16)fmaxf(v.w, 0.f)};
    *(f16x4*)(y + i) = o;
}

__global__ __launch_bounds__(256)
void bnrelu16_kernel(const _Float16* __restrict__ h, const float* __restrict__ sc,
                     const float* __restrict__ sh, _Float16* __restrict__ y) {
    size_t i = (size_t)(blockIdx.x * 256 + threadIdx.x) * 8;   // N*256 total
    if (i >= (size_t)N_NODES * 256) return;
    int col = (int)(i & 255);
    f16x8 v = *(const f16x8*)(h + i);
    float4 s0 = ld4(sc + col), s1 = ld4(sc + col + 4);
    float4 t0 = ld4(sh + col), t1 = ld4(sh + col + 4);
    f16x8 o;
    o[0] = (_Float16)fmaxf(fmaf((float)v[0], s0.x, t0.x), 0.f);
    o[1] = (_Float16)fmaxf(fmaf((float)v[1], s0.y, t0.y), 0.f);
    o[2] = (_Float16)fmaxf(fmaf((float)v[2], s0.z, t0.z), 0.f);
    o[3] = (_Float16)fmaxf(fmaf((float)v[3], s0.w, t0.w), 0.f);
    o[4] = (_Float16)fmaxf(fmaf((float)v[4], s1.x, t1.x), 0.f);
    o[5] = (_Float16)fmaxf(fmaf((float)v[5], s1.y, t1.y), 0.f);
    o[6] = (_Float16)fmaxf(fmaf((float)v[6], s1.z, t1.z), 0.f);
    o[7] = (_Float16)fmaxf(fmaf((float)v[7], s1.w, t1.w), 0.f);
    *(f16x8*)(y + i) = o;
}

// ---------------------------------------------------------------------------
// Fused gather + MLP (degree-sorted rows):
//   stage: agg row = self(BN) + sum_{e} Y[src] || agg_e[n], fp32 accum,
//          depth-2 pipelined 16B loads; rows via perm[] (uniform degree/block).
//   then:  xout = fp16(relu( relu(A@W1+b1) @ W2 + b2 )), + BN stats.
// 32 rows/block, 4 waves each own a 64-col slab; ~19KB LDS.
template <bool BNIN, typename T, int NC>   // DIN = NC*32, K1 = DIN+32
__global__ __launch_bounds__(256)
void fused_mlp_kernel(const T* __restrict__ X, const _Float16* __restrict__ Yg,
                      const int* __restrict__ perm,
                      const int* __restrict__ row_ptr, const int* __restrict__ csr_src,
                      const float* __restrict__ agg_e,
                      const float* __restrict__ bnsc, const float* __restrict__ bnsh,
                      const _Float16* __restrict__ B1, const float* __restrict__ bias1,
                      const _Float16* __restrict__ B2, const float* __restrict__ bias2,
                      _Float16* __restrict__ C, float* __restrict__ bnslot) {
    constexpr int DIN  = NC * 32;
    constexpr int K1   = DIN + 32;
    constexpr int NKT1 = K1 / 32;
    constexpr int CPT  = DIN / 8;        // cols per stage-thread
    constexpr int NV   = CPT / 8;        // f16x8 loads per neighbor
    __shared__ __align__(16) _Float16 sBuf[32 * KSTR];   // A tile, then h1
    __shared__ int sPerm[32];
    const int t = threadIdx.x;
    const int l = t & 63;
    const int w = t >> 6;
    const int lr = l & 15;
    const int lq = l >> 4;
    const int cb = w << 6;

    if (t < 32) sPerm[t] = perm[(blockIdx.x << 5) + t];
    __syncthreads();

    // ---- stage: gather-aggregate directly into LDS (8 threads/row) ----
    {
        const int r = t >> 3, j = t & 7;
        const int gr = sPerm[r];
        if (gr >= 0) {
            float accf[CPT];
#pragma unroll
            for (int c = 0; c < CPT; ++c) accf[c] = 0.f;
            const int beg = row_ptr[gr], end = row_ptr[gr + 1];
            // depth-2 pipelined neighbor loop: pure fp16 adds (relu/BN in Yg)
            int e = beg;
            f16x8 v0[NV];
            if (e < end) {
                const _Float16* sp = Yg + (size_t)csr_src[e] * DIN + j * CPT;
#pragma unroll
                for (int c = 0; c < NV; ++c) v0[c] = *(const f16x8*)(sp + c * 8);
            }
            for (; e < end; ++e) {
                f16x8 v1[NV];
                if (e + 1 < end) {
                    const _Float16* sp = Yg + (size_t)csr_src[e + 1] * DIN + j * CPT;
#pragma unroll
                    for (int c = 0; c < NV; ++c) v1[c] = *(const f16x8*)(sp + c * 8);
                }
#pragma unroll
                for (int c = 0; c < NV; ++c)
#pragma unroll
                    for (int k = 0; k < 8; ++k) accf[c * 8 + k] += (float)v0[c][k];
#pragma unroll
                for (int c = 0; c < NV; ++c) v0[c] = v1[c];
            }
            // self term (BN if BNIN, no relu)
            const T* xp = X + (size_t)gr * DIN + j * CPT;
#pragma unroll
            for (int c2 = 0; c2 < CPT / 4; ++c2) {
                float4 v = ld4(xp + c2 * 4);
                if (BNIN) {
                    float4 sc4 = *(const float4*)(bnsc + j * CPT + c2 * 4);
                    float4 sh4 = *(const float4*)(bnsh + j * CPT + c2 * 4);
                    v.x = fmaf(v.x, sc4.x, sh4.x);
                    v.y = fmaf(v.y, sc4.y, sh4.y);
                    v.z = fmaf(v.z, sc4.z, sh4.z);
                    v.w = fmaf(v.w, sc4.w, sh4.w);
                }
                accf[c2 * 4 + 0] += v.x;
                accf[c2 * 4 + 1] += v.y;
                accf[c2 * 4 + 2] += v.z;
                accf[c2 * 4 + 3] += v.w;
            }
            // store fp16 row to LDS
#pragma unroll
            for (int c = 0; c < NV; ++c) {
                f16x8 o;
#pragma unroll
                for (int k = 0; k < 8; ++k) o[k] = (_Float16)accf[c * 8 + k];
                *(f16x8*)&sBuf[r * KSTR + j * CPT + c * 8] = o;
            }
            float4 ev = *(const float4*)(agg_e + (size_t)gr * DE + (j << 2));
            st4h(&sBuf[r * KSTR + DIN + (j << 2)], ev);
        } else {
            f16x8 z8 = {0, 0, 0, 0, 0, 0, 0, 0};
#pragma unroll
            for (int c = 0; c < NV; ++c)
                *(f16x8*)&sBuf[r * KSTR + j * CPT + c * 8] = z8;
            f16x4 z4 = {0, 0, 0, 0};
            *(f16x4*)&sBuf[r * KSTR + DIN + (j << 2)] = z4;
        }
    }
    __syncthreads();

    // ---- phase 1: A @ W1 (barrier-free) ----
    f32x4 acc1[2][4];
#pragma unroll
    for (int mt = 0; mt < 2; ++mt)
#pragma unroll
        for (int nt = 0; nt < 4; ++nt) acc1[mt][nt] = (f32x4){0.f, 0.f, 0.f, 0.f};
#pragma unroll
    for (int kt = 0; kt < NKT1; ++kt) {
        f16x8 af[2], bf[4];
#pragma unroll
        for (int mt = 0; mt < 2; ++mt)
            af[mt] = *(const f16x8*)&sBuf[(mt * 16 + lr) * KSTR + (kt << 5) + (lq << 3)];
        const size_t bb = ((size_t)(kt * 16 + (w << 2))) * 512 + (l << 3);
#pragma unroll
        for (int nt = 0; nt < 4; ++nt)
            bf[nt] = *(const f16x8*)(B1 + bb + nt * 512);
#pragma unroll
        for (int mt = 0; mt < 2; ++mt)
#pragma unroll
            for (int nt = 0; nt < 4; ++nt)
                acc1[mt][nt] = __builtin_amdgcn_mfma_f32_16x16x32_f16(
                    af[mt], bf[nt], acc1[mt][nt], 0, 0, 0);
    }
    __syncthreads();   // A tile dead; reuse plane for h1

    // ---- epilogue 1: relu(h1) -> LDS fp16 ----
#pragma unroll
    for (int nt = 0; nt < 4; ++nt) {
        int col = cb + nt * 16 + lr;
        float bv = bias1[col];
#pragma unroll
        for (int mt = 0; mt < 2; ++mt)
#pragma unroll
            for (int i = 0; i < 4; ++i) {
                int rr = mt * 16 + lq * 4 + i;
                sBuf[rr * KSTR + col] = (_Float16)fmaxf(acc1[mt][nt][i] + bv, 0.f);
            }
    }
    __syncthreads();

    // ---- phase 2: h1 @ W2 (barrier-free) ----
    f32x4 acc2[2][4];
#pragma unroll
    for (int mt = 0; mt < 2; ++mt)
#pragma unroll
        for (int nt = 0; nt < 4; ++nt) acc2[mt][nt] = (f32x4){0.f, 0.f, 0.f, 0.f};
#pragma unroll
    for (int kt = 0; kt < 8; ++kt) {
        f16x8 af[2], bf[4];
#pragma unroll
        for (int mt = 0; mt < 2; ++mt)
            af[mt] = *(const f16x8*)&sBuf[(mt * 16 + lr) * KSTR + (kt << 5) + (lq << 3)];
        const size_t bb = ((size_t)(kt * 16 + (w << 2))) * 512 + (l << 3);
#pragma unroll
        for (int nt = 0; nt < 4; ++nt)
            bf[nt] = *(const f16x8*)(B2 + bb + nt * 512);
#pragma unroll
        for (int mt = 0; mt < 2; ++mt)
#pragma unroll
            for (int nt = 0; nt < 4; ++nt)
                acc2[mt][nt] = __builtin_amdgcn_mfma_f32_16x16x32_f16(
                    af[mt], bf[nt], acc2[mt][nt], 0, 0, 0);
    }

    // ---- epilogue 2: bias + relu + fp16 store + BN stats ----
    float* slot = bnslot + (size_t)(blockIdx.x & (BN_SLOTS - 1)) * 512;
#pragma unroll
    for (int nt = 0; nt < 4; ++nt) {
        int col = cb + nt * 16 + lr;
        float bv = bias2[col];
        float s = 0.f, qq = 0.f;
#pragma unroll
        for (int mt = 0; mt < 2; ++mt)
#pragma unroll
            for (int i = 0; i < 4; ++i) {
                int row = sPerm[mt * 16 + lq * 4 + i];
                if (row >= 0) {
                    float o = fmaxf(acc2[mt][nt][i] + bv, 0.f);
                    C[(size_t)row * 256 + col] = (_Float16)o;
                    s += o; qq += o * o;
                }
            }
        s += __shfl_xor(s, 16); s += __shfl_xor(s, 32);
        qq += __shfl_xor(qq, 16); qq += __shfl_xor(qq, 32);
        if (lq == 0) {
            atomicAdd(&slot[col], s);
            atomicAdd(&slot[256 + col], qq);
        }
    }
}

// reduce BN_SLOTS slots -> scale/shift
__global__ void bn_finalize_kernel(const float* __restrict__ slots,
                                   const float* __restrict__ g, const float* __restrict__ beta,
                                   float* __restrict__ scale, float* __restrict__ shift) {
    int c = threadIdx.x;
    float s = 0.f, q = 0.f;
    for (int k = 0; k < BN_SLOTS; ++k) {
        s += slots[(size_t)k * 512 + c];
        q += slots[(size_t)k * 512 + 256 + c];
    }
    float mu = s * (1.0f / N_NODES);
    float var = q * (1.0f / N_NODES) - mu * mu;
    float rstd = rsqrtf(var + 1e-5f);
    float sc = g[c] * rstd;
    scale[c] = sc;
    shift[c] = beta[c] - mu * sc;
}

// segmented sqrt-pool (fp16 input) with BN applied at load; fp32 output
__global__ __launch_bounds__(256)
void pool_seg_kernel(const _Float16* __restrict__ h, const int* __restrict__ ptr,
                     const float* __restrict__ bnsc, const float* __restrict__ bnsh,
                     float* __restrict__ out, int nseg) {
    int t = threadIdx.x;
    int g = t >> 6;
    int j = t & 63;
    int s = blockIdx.x * 4 + g;
    if (s >= nseg) return;
    int beg = ptr[s], end = ptr[s + 1];
    int col = j << 2;
    float4 sc = *(const float4*)(bnsc + col);
    float4 sh = *(const float4*)(bnsh + col);
    float4 acc = {0.f, 0.f, 0.f, 0.f};
    for (int i = beg; i < end; ++i) {
        float4 v = ld4(h + (size_t)i * 256 + col);
        acc.x += fmaf(v.x, sc.x, sh.x);
        acc.y += fmaf(v.y, sc.y, sh.y);
        acc.z += fmaf(v.z, sc.z, sh.z);
        acc.w += fmaf(v.w, sc.w, sh.w);
    }
    float w = rsqrtf(fmaxf((float)(end - beg), 1.0f));
    float4 o = {acc.x * w, acc.y * w, acc.z * w, acc.w * w};
    *(float4*)(out + (size_t)s * 256 + col) = o;
}

// ---------------------------------------------------------------------------
extern "C" void kernel_launch(void* const* d_in, const int* in_sizes, int n_in,
                              void* d_out, int out_size, void* d_ws, size_t ws_size,
                              hipStream_t stream) {
    const float* x  = (const float*)d_in[0];
    const float* ea = (const float*)d_in[1];
    const int*   ei = (const int*)d_in[2];
    const int*   fb = (const int*)d_in[3];
    const int*   gb = (const int*)d_in[4];
    const float* W1[3]   = {(const float*)d_in[5],  (const float*)d_in[11], (const float*)d_in[17]};
    const float* B1[3]   = {(const float*)d_in[6],  (const float*)d_in[12], (const float*)d_in[18]};
    const float* W2[3]   = {(const float*)d_in[7],  (const float*)d_in[13], (const float*)d_in[19]};
    const float* B2[3]   = {(const float*)d_in[8],  (const float*)d_in[14], (const float*)d_in[20]};
    const float* G[3]    = {(const float*)d_in[9],  (const float*)d_in[15], (const float*)d_in[21]};
    const float* BETA[3] = {(const float*)d_in[10], (const float*)d_in[16], (const float*)d_in[22]};

    const int FIN[3] = {160, 288, 288};
    const int NBLK = (N_NODES + 255) / 256;      // scan blocks

    float* ws = (float*)d_ws;
    size_t off = 0;
    _Float16* bufA = (_Float16*)(ws + off); off += (size_t)N_NODES * 128;  // N x 256 fp16
    _Float16* bufB = (_Float16*)(ws + off); off += (size_t)N_NODES * 128;
    _Float16* ybuf = (_Float16*)(ws + off); off += (size_t)N_NODES * 128;  // pre-activation Y
    float* agg_e = ws + off; off += (size_t)N_NODES * DE;
    float* bnss  = ws + off; off += 3 * 512;                 // per layer: scale|shift
    float* bnslots = ws + off; off += (size_t)3 * BN_SLOTS * 512;
    _Float16* w1f[3]; _Float16* w2f[3];
    {
        _Float16* sw = (_Float16*)(ws + off);
        _Float16* sw0 = sw;
        for (int l = 0; l < 3; ++l) { w1f[l] = sw; sw += 256 * FIN[l]; }
        for (int l = 0; l < 3; ++l) { w2f[l] = sw; sw += 256 * 256; }
        off += (size_t)(sw - sw0 + 1) / 2;
    }
    int* iw      = (int*)(ws + off);
    int* row_ptr = iw;                     iw += N_NODES + 1;
    int* deg     = iw;                     iw += N_NODES;
    int* fill    = iw;                     iw += N_NODES;
    int* csr_src = iw;                     iw += N_EDGES;
    int* csr_eid = iw;                     iw += N_EDGES;
    int* frag_ptr = iw;                    iw += N_FRAG + 1;
    int* graph_ptr = iw;                   iw += N_GRAPH + 1;
    int* bsum    = iw;                     iw += NBLK;
    int* perm    = iw;                     iw += N_NODES + 16;
    int* hist    = iw;                     iw += 64;
    int* fill64  = iw;                     iw += 64;

    hipMemsetAsync(deg, 0, 2 * N_NODES * sizeof(int), stream);
    hipMemsetAsync(hist, 0, 128 * sizeof(int), stream);
    hipMemsetAsync(bnslots, 0, (size_t)3 * BN_SLOTS * 512 * sizeof(float), stream);

    // weight fragment-swizzle to fp16 (once per layer)
    for (int l = 0; l < 3; ++l) {
        bs16_kernel<<<(FIN[l] * 256 + 255) / 256, 256, 0, stream>>>(W1[l], w1f[l], FIN[l]);
        bs16_kernel<<<(256 * 256 + 255) / 256, 256, 0, stream>>>(W2[l], w2f[l], 256);
    }

    // CSR build (hierarchical scan)
    count_deg_kernel<<<(N_EDGES + 255) / 256, 256, 0, stream>>>(ei, deg);
    block_sum_kernel<<<NBLK, 256, 0, stream>>>(deg, bsum);
    top_scan_kernel<<<1, 256, 0, stream>>>(bsum, NBLK);
    final_scan_kernel<<<NBLK, 256, 0, stream>>>(deg, bsum, row_ptr);
    fill_csr_kernel<<<(N_EDGES + 255) / 256, 256, 0, stream>>>(ei, row_ptr, fill, csr_src, csr_eid);

    // degree-sorted permutation (LDS-aggregated counting sort)
    deg_hist_kernel<<<NBLK, 256, 0, stream>>>(deg, hist);
    binscan_kernel<<<1, 64, 0, stream>>>(hist, perm);
    scatter_perm_kernel<<<NBLK, 256, 0, stream>>>(deg, hist, fill64, perm);

    segptr_kernel<<<(N_FRAG + 1 + 255) / 256, 256, 0, stream>>>(fb, N_FRAG, frag_ptr);
    segptr_kernel<<<(N_GRAPH + 1 + 255) / 256, 256, 0, stream>>>(gb, N_GRAPH, graph_ptr);

    edge_gather_kernel<<<(N_NODES + 31) / 32, 256, 0, stream>>>(ea, row_ptr, csr_eid, agg_e);

    const int nblk_mlp = (N_NODES + 31) / 32;    // 1563 blocks, 32 rows each
    // layer 0: Y0 = fp16(relu(x)), self = x (fp32)
    relu16_f32_kernel<<<(N_NODES * 128 / 4 + 255) / 256, 256, 0, stream>>>(x, ybuf);
    {
        float* slotsL = bnslots;
        fused_mlp_kernel<false, float, 4><<<nblk_mlp, 256, 0, stream>>>(
            x, ybuf, perm, row_ptr, csr_src, agg_e, nullptr, nullptr,
            w1f[0], B1[0], w2f[0], B2[0], bufA, slotsL);
        bn_finalize_kernel<<<1, 256, 0, stream>>>(slotsL, G[0], BETA[0], bnss, bnss + 256);
    }
    // layer 1: Y = fp16(relu(BN0(bufA))), self = BN0(bufA)
    {
        float* slotsL = bnslots + (size_t)1 * BN_SLOTS * 512;
        const float* psc = bnss, * psh = bnss + 256;
        bnrelu16_kernel<<<(N_NODES * 256 / 8 + 255) / 256, 256, 0, stream>>>(bufA, psc, psh, ybuf);
        fused_mlp_kernel<true, _Float16, 8><<<nblk_mlp, 256, 0, stream>>>(
            bufA, ybuf, perm, row_ptr, csr_src, agg_e, psc, psh,
            w1f[1], B1[1], w2f[1], B2[1], bufB, slotsL);
        bn_finalize_kernel<<<1, 256, 0, stream>>>(slotsL, G[1], BETA[1], bnss + 512, bnss + 768);
    }
    // layer 2: Y = fp16(relu(BN1(bufB))), self = BN1(bufB)
    {
        float* slotsL = bnslots + (size_t)2 * BN_SLOTS * 512;
        const float* psc = bnss + 512, * psh = bnss + 768;
        bnrelu16_kernel<<<(N_NODES * 256 / 8 + 255) / 256, 256, 0, stream>>>(bufB, psc, psh, ybuf);
        fused_mlp_kernel<true, _Float16, 8><<<nblk_mlp, 256, 0, stream>>>(
            bufB, ybuf, perm, row_ptr, csr_src, agg_e, psc, psh,
            w1f[2], B1[2], w2f[2], B2[2], bufA, slotsL);
        bn_finalize_kernel<<<1, 256, 0, stream>>>(slotsL, G[2], BETA[2], bnss + 1024, bnss + 1280);
    }

    const float* fsc = bnss + 2 * 512;   // layer-2 BN scale/shift
    const float* fsh = fsc + 256;
    pool_seg_kernel<<<(N_FRAG + 3) / 4, 256, 0, stream>>>(bufA, frag_ptr, fsc, fsh,
                                                          (float*)d_out, N_FRAG);
    pool_seg_kernel<<<(N_GRAPH + 3) / 4, 256, 0, stream>>>(bufA, graph_ptr, fsc, fsh,
                                                           (float*)d_out + (size_t)N_FRAG * 256, N_GRAPH);
}

// Round 5
// 423.272 us; speedup vs baseline: 2.0442x; 1.0786x over previous
//
#include <hip/hip_runtime.h>

#define N_NODES 50000
#define N_EDGES 200000
#define DE 32
#define N_FRAG 10000
#define N_GRAPH 2000
#define BN_SLOTS 32
#define KSTR 296   // LDS stride (fp16 elems) for the 32-row A/h1 plane

typedef _Float16 f16x8 __attribute__((ext_vector_type(8)));
typedef _Float16 f16x4 __attribute__((ext_vector_type(4)));
typedef __attribute__((ext_vector_type(4))) float f32x4;

__device__ __forceinline__ float4 ld4(const float* p) { return *(const float4*)p; }
__device__ __forceinline__ float4 ld4(const _Float16* p) {
    f16x4 h = *(const f16x4*)p;
    float4 v; v.x = (float)h[0]; v.y = (float)h[1]; v.z = (float)h[2]; v.w = (float)h[3];
    return v;
}
__device__ __forceinline__ void st4h(_Float16* p, float4 v) {
    f16x4 h = {(_Float16)v.x, (_Float16)v.y, (_Float16)v.z, (_Float16)v.w};
    *(f16x4*)p = h;
}

// ---------------------------------------------------------------------------
// CSR build: in-degree count, hierarchical scan, fill
__global__ __launch_bounds__(256)
void count_deg_kernel(const int* __restrict__ ei, int* __restrict__ deg) {
    int e = blockIdx.x * 256 + threadIdx.x;
    if (e < N_EDGES) atomicAdd(&deg[ei[N_EDGES + e]], 1);
}

__global__ __launch_bounds__(256)
void block_sum_kernel(const int* __restrict__ deg, int* __restrict__ bsum) {
    int i = blockIdx.x * 256 + threadIdx.x;
    int v = (i < N_NODES) ? deg[i] : 0;
#pragma unroll
    for (int o = 1; o < 64; o <<= 1) v += __shfl_xor(v, o);
    __shared__ int wsum[4];
    if ((threadIdx.x & 63) == 0) wsum[threadIdx.x >> 6] = v;
    __syncthreads();
    if (threadIdx.x == 0) bsum[blockIdx.x] = wsum[0] + wsum[1] + wsum[2] + wsum[3];
}

__global__ __launch_bounds__(256)
void top_scan_kernel(int* __restrict__ bsum, int nb) {
    __shared__ int s[256];
    int t = threadIdx.x;
    s[t] = (t < nb) ? bsum[t] : 0;
    __syncthreads();
    for (int o = 1; o < 256; o <<= 1) {
        int v = s[t];
        int a = (t >= o) ? s[t - o] : 0;
        __syncthreads();
        s[t] = v + a;
        __syncthreads();
    }
    if (t < nb) bsum[t] = (t > 0) ? s[t - 1] : 0;
}

__global__ __launch_bounds__(256)
void final_scan_kernel(const int* __restrict__ deg, const int* __restrict__ bsum,
                       int* __restrict__ ptr) {
    __shared__ int s[256];
    int i = blockIdx.x * 256 + threadIdx.x;
    int t = threadIdx.x;
    int v = (i < N_NODES) ? deg[i] : 0;
    s[t] = v;
    __syncthreads();
    for (int o = 1; o < 256; o <<= 1) {
        int x = s[t];
        int a = (t >= o) ? s[t - o] : 0;
        __syncthreads();
        s[t] = x + a;
        __syncthreads();
    }
    int incl = s[t];
    int base = bsum[blockIdx.x];
    if (i < N_NODES) ptr[i] = base + incl - v;
    if (i == N_NODES - 1) ptr[N_NODES] = base + incl;
}

__global__ __launch_bounds__(256)
void fill_csr_kernel(const int* __restrict__ ei, const int* __restrict__ row_ptr,
                     int* __restrict__ fill, int* __restrict__ csr_src,
                     int* __restrict__ csr_eid) {
    int e = blockIdx.x * 256 + threadIdx.x;
    if (e >= N_EDGES) return;
    int dst = ei[N_EDGES + e];
    int pos = row_ptr[dst] + atomicAdd(&fill[dst], 1);
    csr_src[pos] = ei[e];
    csr_eid[pos] = e;
}

__global__ __launch_bounds__(256)
void segptr_kernel(const int* __restrict__ batch, int nseg, int* __restrict__ ptr) {
    int s = blockIdx.x * 256 + threadIdx.x;
    if (s > nseg) return;
    int lo = 0, hi = N_NODES;
    while (lo < hi) {
        int mid = (lo + hi) >> 1;
        if (batch[mid] < s) lo = mid + 1; else hi = mid;
    }
    ptr[s] = lo;
}

// ---------------------------------------------------------------------------
// W [K][256] fp32 -> fragment-swizzled fp16 BS:
// BS[kt][cg][lane][j] = fp16(W[kt*32 + (lane>>4)*8 + j][cg*16 + (lane&15)])
__global__ __launch_bounds__(256)
void bs16_kernel(const float* __restrict__ W, _Float16* __restrict__ BS, int K) {
    int id = blockIdx.x * 256 + threadIdx.x;
    if (id >= K * 256) return;
    int j  = id & 7;
    int l  = (id >> 3) & 63;
    int cg = (id >> 9) & 15;
    int kt = id >> 13;
    int col = cg * 16 + (l & 15);
    int k   = kt * 32 + (l >> 4) * 8 + j;
    BS[id] = (_Float16)W[(size_t)k * 256 + col];
}

// ---------------------------------------------------------------------------
// agg_e[n] = sum over incoming edges of relu(edge_attr[e])  [N,32]
__global__ __launch_bounds__(256)
void edge_gather_kernel(const float* __restrict__ ea, const int* __restrict__ row_ptr,
                        const int* __restrict__ csr_eid, float* __restrict__ agg_e) {
    int t = threadIdx.x;
    int g = t >> 3;
    int j = t & 7;
    int n = blockIdx.x * 32 + g;
    if (n >= N_NODES) return;
    int col = j << 2;
    float4 acc = {0.f, 0.f, 0.f, 0.f};
    int beg = row_ptr[n], end = row_ptr[n + 1];
    for (int e = beg; e < end; ++e) {
        int eid = csr_eid[e];
        float4 v = *(const float4*)(ea + (size_t)eid * DE + col);
        acc.x += fmaxf(v.x, 0.f);
        acc.y += fmaxf(v.y, 0.f);
        acc.z += fmaxf(v.z, 0.f);
        acc.w += fmaxf(v.w, 0.f);
    }
    *(float4*)(agg_e + (size_t)n * DE + col) = acc;
}

// ---------------------------------------------------------------------------
// Pre-activation buffers for the gather: Y0 = fp16(relu(x)) (layer 0),
// Y = fp16(relu(sc*h+sh)) (layers 1,2). Gather loop then is pure fp16 adds.
__global__ __launch_bounds__(256)
void relu16_f32_kernel(const float* __restrict__ x, _Float16* __restrict__ y) {
    size_t i = (size_t)(blockIdx.x * 256 + threadIdx.x) * 4;   // N*128 total
    if (i >= (size_t)N_NODES * 128) return;
    float4 v = ld4(x + i);
    f16x4 o = {(_Float16)fmaxf(v.x, 0.f), (_Float16)fmaxf(v.y, 0.f),
               (_Float16)fmaxf(v.z, 0.f), (_Float16)fmaxf(v.w, 0.f)};
    *(f16x4*)(y + i) = o;
}

__global__ __launch_bounds__(256)
void bnrelu16_kernel(const _Float16* __restrict__ h, const float* __restrict__ sc,
                     const float* __restrict__ sh, _Float16* __restrict__ y) {
    size_t i = (size_t)(blockIdx.x * 256 + threadIdx.x) * 8;   // N*256 total
    if (i >= (size_t)N_NODES * 256) return;
    int col = (int)(i & 255);
    f16x8 v = *(const f16x8*)(h + i);
    float4 s0 = ld4(sc + col), s1 = ld4(sc + col + 4);
    float4 t0 = ld4(sh + col), t1 = ld4(sh + col + 4);
    f16x8 o;
    o[0] = (_Float16)fmaxf(fmaf((float)v[0], s0.x, t0.x), 0.f);
    o[1] = (_Float16)fmaxf(fmaf((float)v[1], s0.y, t0.y), 0.f);
    o[2] = (_Float16)fmaxf(fmaf((float)v[2], s0.z, t0.z), 0.f);
    o[3] = (_Float16)fmaxf(fmaf((float)v[3], s0.w, t0.w), 0.f);
    o[4] = (_Float16)fmaxf(fmaf((float)v[4], s1.x, t1.x), 0.f);
    o[5] = (_Float16)fmaxf(fmaf((float)v[5], s1.y, t1.y), 0.f);
    o[6] = (_Float16)fmaxf(fmaf((float)v[6], s1.z, t1.z), 0.f);
    o[7] = (_Float16)fmaxf(fmaf((float)v[7], s1.w, t1.w), 0.f);
    *(f16x8*)(y + i) = o;
}

// ---------------------------------------------------------------------------
// Fused gather + MLP (occupancy-first build):
//   stage: agg row = self(BN) + sum_{e} Y[src] || agg_e[n]; neighbor sum in
//          PACKED fp16 (v_pk_add_f16) to keep stage regs low; self in fp32.
//   then:  xout = fp16(relu( relu(A@W1+b1) @ W2 + b2 )), + BN stats.
// 32 rows/block, 4 waves each own a 64-col slab; ~18.9KB LDS.
// __launch_bounds__(256,8): cap 64 VGPR -> 8 waves/SIMD, 8 blocks/CU.
// (R0..R4 data: occ x dur is constant for this kernel -> throughput is
//  proportional to resident waves; VGPR 88 was the limiter.)
template <bool BNIN, typename T, int NC>   // DIN = NC*32, K1 = DIN+32
__global__ __launch_bounds__(256, 8)
void fused_mlp_kernel(const T* __restrict__ X, const _Float16* __restrict__ Yg,
                      const int* __restrict__ row_ptr, const int* __restrict__ csr_src,
                      const float* __restrict__ agg_e,
                      const float* __restrict__ bnsc, const float* __restrict__ bnsh,
                      const _Float16* __restrict__ B1, const float* __restrict__ bias1,
                      const _Float16* __restrict__ B2, const float* __restrict__ bias2,
                      _Float16* __restrict__ C, float* __restrict__ bnslot) {
    constexpr int DIN  = NC * 32;
    constexpr int K1   = DIN + 32;
    constexpr int NKT1 = K1 / 32;
    constexpr int CPT  = DIN / 8;        // cols per stage-thread
    constexpr int NV   = CPT / 8;        // f16x8 chunks per stage-thread
    __shared__ __align__(16) _Float16 sBuf[32 * KSTR];   // A tile, then h1
    const int t = threadIdx.x;
    const int l = t & 63;
    const int w = t >> 6;
    const int lr = l & 15;
    const int lq = l >> 4;
    const int row0 = blockIdx.x << 5;   // 32 rows/block
    const int cb = w << 6;

    // ---- stage: gather-aggregate directly into LDS (8 threads/row) ----
    {
        const int r = t >> 3, j = t & 7;
        const int gr = row0 + r;
        if (gr < N_NODES) {
            f16x8 acc16[NV];
#pragma unroll
            for (int c = 0; c < NV; ++c) acc16[c] = (f16x8){0, 0, 0, 0, 0, 0, 0, 0};
            const int beg = row_ptr[gr], end = row_ptr[gr + 1];
            for (int e = beg; e < end; ++e) {
                const _Float16* sp = Yg + (size_t)csr_src[e] * DIN + j * CPT;
#pragma unroll
                for (int c = 0; c < NV; ++c) acc16[c] += *(const f16x8*)(sp + c * 8);
            }
            // self term (BN if BNIN, no relu) + fp16 neighbor sum, 8 cols/chunk
            const T* xp = X + (size_t)gr * DIN + j * CPT;
#pragma unroll
            for (int c = 0; c < NV; ++c) {
                float4 v0 = ld4(xp + c * 8);
                float4 v1 = ld4(xp + c * 8 + 4);
                if (BNIN) {
                    float4 sa = *(const float4*)(bnsc + j * CPT + c * 8);
                    float4 sb = *(const float4*)(bnsc + j * CPT + c * 8 + 4);
                    float4 ta = *(const float4*)(bnsh + j * CPT + c * 8);
                    float4 tb = *(const float4*)(bnsh + j * CPT + c * 8 + 4);
                    v0.x = fmaf(v0.x, sa.x, ta.x);
                    v0.y = fmaf(v0.y, sa.y, ta.y);
                    v0.z = fmaf(v0.z, sa.z, ta.z);
                    v0.w = fmaf(v0.w, sa.w, ta.w);
                    v1.x = fmaf(v1.x, sb.x, tb.x);
                    v1.y = fmaf(v1.y, sb.y, tb.y);
                    v1.z = fmaf(v1.z, sb.z, tb.z);
                    v1.w = fmaf(v1.w, sb.w, tb.w);
                }
                f16x8 o;
                o[0] = (_Float16)(v0.x + (float)acc16[c][0]);
                o[1] = (_Float16)(v0.y + (float)acc16[c][1]);
                o[2] = (_Float16)(v0.z + (float)acc16[c][2]);
                o[3] = (_Float16)(v0.w + (float)acc16[c][3]);
                o[4] = (_Float16)(v1.x + (float)acc16[c][4]);
                o[5] = (_Float16)(v1.y + (float)acc16[c][5]);
                o[6] = (_Float16)(v1.z + (float)acc16[c][6]);
                o[7] = (_Float16)(v1.w + (float)acc16[c][7]);
                *(f16x8*)&sBuf[r * KSTR + j * CPT + c * 8] = o;
            }
            float4 ev = *(const float4*)(agg_e + (size_t)gr * DE + (j << 2));
            st4h(&sBuf[r * KSTR + DIN + (j << 2)], ev);
        } else {
            f16x8 z8 = {0, 0, 0, 0, 0, 0, 0, 0};
#pragma unroll
            for (int c = 0; c < NV; ++c)
                *(f16x8*)&sBuf[r * KSTR + j * CPT + c * 8] = z8;
            f16x4 z4 = {0, 0, 0, 0};
            *(f16x4*)&sBuf[r * KSTR + DIN + (j << 2)] = z4;
        }
    }
    __syncthreads();

    // ---- phase 1: A @ W1 (barrier-free) ----
    f32x4 acc1[2][4];
#pragma unroll
    for (int mt = 0; mt < 2; ++mt)
#pragma unroll
        for (int nt = 0; nt < 4; ++nt) acc1[mt][nt] = (f32x4){0.f, 0.f, 0.f, 0.f};
#pragma unroll
    for (int kt = 0; kt < NKT1; ++kt) {
        f16x8 af[2], bf[4];
#pragma unroll
        for (int mt = 0; mt < 2; ++mt)
            af[mt] = *(const f16x8*)&sBuf[(mt * 16 + lr) * KSTR + (kt << 5) + (lq << 3)];
        const size_t bb = ((size_t)(kt * 16 + (w << 2))) * 512 + (l << 3);
#pragma unroll
        for (int nt = 0; nt < 4; ++nt)
            bf[nt] = *(const f16x8*)(B1 + bb + nt * 512);
#pragma unroll
        for (int mt = 0; mt < 2; ++mt)
#pragma unroll
            for (int nt = 0; nt < 4; ++nt)
                acc1[mt][nt] = __builtin_amdgcn_mfma_f32_16x16x32_f16(
                    af[mt], bf[nt], acc1[mt][nt], 0, 0, 0);
    }
    __syncthreads();   // A tile dead; reuse plane for h1

    // ---- epilogue 1: relu(h1) -> LDS fp16 ----
#pragma unroll
    for (int nt = 0; nt < 4; ++nt) {
        int col = cb + nt * 16 + lr;
        float bv = bias1[col];
#pragma unroll
        for (int mt = 0; mt < 2; ++mt)
#pragma unroll
            for (int i = 0; i < 4; ++i) {
                int rr = mt * 16 + lq * 4 + i;
                sBuf[rr * KSTR + col] = (_Float16)fmaxf(acc1[mt][nt][i] + bv, 0.f);
            }
    }
    __syncthreads();

    // ---- phase 2: h1 @ W2 (barrier-free) ----
    f32x4 acc2[2][4];
#pragma unroll
    for (int mt = 0; mt < 2; ++mt)
#pragma unroll
        for (int nt = 0; nt < 4; ++nt) acc2[mt][nt] = (f32x4){0.f, 0.f, 0.f, 0.f};
#pragma unroll
    for (int kt = 0; kt < 8; ++kt) {
        f16x8 af[2], bf[4];
#pragma unroll
        for (int mt = 0; mt < 2; ++mt)
            af[mt] = *(const f16x8*)&sBuf[(mt * 16 + lr) * KSTR + (kt << 5) + (lq << 3)];
        const size_t bb = ((size_t)(kt * 16 + (w << 2))) * 512 + (l << 3);
#pragma unroll
        for (int nt = 0; nt < 4; ++nt)
            bf[nt] = *(const f16x8*)(B2 + bb + nt * 512);
#pragma unroll
        for (int mt = 0; mt < 2; ++mt)
#pragma unroll
            for (int nt = 0; nt < 4; ++nt)
                acc2[mt][nt] = __builtin_amdgcn_mfma_f32_16x16x32_f16(
                    af[mt], bf[nt], acc2[mt][nt], 0, 0, 0);
    }

    // ---- epilogue 2: bias + relu + fp16 store + BN stats ----
    float* slot = bnslot + (size_t)(blockIdx.x & (BN_SLOTS - 1)) * 512;
#pragma unroll
    for (int nt = 0; nt < 4; ++nt) {
        int col = cb + nt * 16 + lr;
        float bv = bias2[col];
        float s = 0.f, qq = 0.f;
#pragma unroll
        for (int mt = 0; mt < 2; ++mt)
#pragma unroll
            for (int i = 0; i < 4; ++i) {
                int row = row0 + mt * 16 + lq * 4 + i;
                if (row < N_NODES) {
                    float o = fmaxf(acc2[mt][nt][i] + bv, 0.f);
                    C[(size_t)row * 256 + col] = (_Float16)o;
                    s += o; qq += o * o;
                }
            }
        s += __shfl_xor(s, 16); s += __shfl_xor(s, 32);
        qq += __shfl_xor(qq, 16); qq += __shfl_xor(qq, 32);
        if (lq == 0) {
            atomicAdd(&slot[col], s);
            atomicAdd(&slot[256 + col], qq);
        }
    }
}

// reduce BN_SLOTS slots -> scale/shift
__global__ void bn_finalize_kernel(const float* __restrict__ slots,
                                   const float* __restrict__ g, const float* __restrict__ beta,
                                   float* __restrict__ scale, float* __restrict__ shift) {
    int c = threadIdx.x;
    float s = 0.f, q = 0.f;
    for (int k = 0; k < BN_SLOTS; ++k) {
        s += slots[(size_t)k * 512 + c];
        q += slots[(size_t)k * 512 + 256 + c];
    }
    float mu = s * (1.0f / N_NODES);
    float var = q * (1.0f / N_NODES) - mu * mu;
    float rstd = rsqrtf(var + 1e-5f);
    float sc = g[c] * rstd;
    scale[c] = sc;
    shift[c] = beta[c] - mu * sc;
}

// segmented sqrt-pool (fp16 input) with BN applied at load; fp32 output
__global__ __launch_bounds__(256)
void pool_seg_kernel(const _Float16* __restrict__ h, const int* __restrict__ ptr,
                     const float* __restrict__ bnsc, const float* __restrict__ bnsh,
                     float* __restrict__ out, int nseg) {
    int t = threadIdx.x;
    int g = t >> 6;
    int j = t & 63;
    int s = blockIdx.x * 4 + g;
    if (s >= nseg) return;
    int beg = ptr[s], end = ptr[s + 1];
    int col = j << 2;
    float4 sc = *(const float4*)(bnsc + col);
    float4 sh = *(const float4*)(bnsh + col);
    float4 acc = {0.f, 0.f, 0.f, 0.f};
    for (int i = beg; i < end; ++i) {
        float4 v = ld4(h + (size_t)i * 256 + col);
        acc.x += fmaf(v.x, sc.x, sh.x);
        acc.y += fmaf(v.y, sc.y, sh.y);
        acc.z += fmaf(v.z, sc.z, sh.z);
        acc.w += fmaf(v.w, sc.w, sh.w);
    }
    float w = rsqrtf(fmaxf((float)(end - beg), 1.0f));
    float4 o = {acc.x * w, acc.y * w, acc.z * w, acc.w * w};
    *(float4*)(out + (size_t)s * 256 + col) = o;
}

// ---------------------------------------------------------------------------
extern "C" void kernel_launch(void* const* d_in, const int* in_sizes, int n_in,
                              void* d_out, int out_size, void* d_ws, size_t ws_size,
                              hipStream_t stream) {
    const float* x  = (const float*)d_in[0];
    const float* ea = (const float*)d_in[1];
    const int*   ei = (const int*)d_in[2];
    const int*   fb = (const int*)d_in[3];
    const int*   gb = (const int*)d_in[4];
    const float* W1[3]   = {(const float*)d_in[5],  (const float*)d_in[11], (const float*)d_in[17]};
    const float* B1[3]   = {(const float*)d_in[6],  (const float*)d_in[12], (const float*)d_in[18]};
    const float* W2[3]   = {(const float*)d_in[7],  (const float*)d_in[13], (const float*)d_in[19]};
    const float* B2[3]   = {(const float*)d_in[8],  (const float*)d_in[14], (const float*)d_in[20]};
    const float* G[3]    = {(const float*)d_in[9],  (const float*)d_in[15], (const float*)d_in[21]};
    const float* BETA[3] = {(const float*)d_in[10], (const float*)d_in[16], (const float*)d_in[22]};

    const int FIN[3] = {160, 288, 288};
    const int NBLK = (N_NODES + 255) / 256;      // scan blocks

    float* ws = (float*)d_ws;
    size_t off = 0;
    _Float16* bufA = (_Float16*)(ws + off); off += (size_t)N_NODES * 128;  // N x 256 fp16
    _Float16* bufB = (_Float16*)(ws + off); off += (size_t)N_NODES * 128;
    _Float16* ybuf = (_Float16*)(ws + off); off += (size_t)N_NODES * 128;  // pre-activation Y
    float* agg_e = ws + off; off += (size_t)N_NODES * DE;
    float* bnss  = ws + off; off += 3 * 512;                 // per layer: scale|shift
    float* bnslots = ws + off; off += (size_t)3 * BN_SLOTS * 512;
    _Float16* w1f[3]; _Float16* w2f[3];
    {
        _Float16* sw = (_Float16*)(ws + off);
        _Float16* sw0 = sw;
        for (int l = 0; l < 3; ++l) { w1f[l] = sw; sw += 256 * FIN[l]; }
        for (int l = 0; l < 3; ++l) { w2f[l] = sw; sw += 256 * 256; }
        off += (size_t)(sw - sw0 + 1) / 2;
    }
    int* iw      = (int*)(ws + off);
    int* row_ptr = iw;                     iw += N_NODES + 1;
    int* deg     = iw;                     iw += N_NODES;
    int* fill    = iw;                     iw += N_NODES;
    int* csr_src = iw;                     iw += N_EDGES;
    int* csr_eid = iw;                     iw += N_EDGES;
    int* frag_ptr = iw;                    iw += N_FRAG + 1;
    int* graph_ptr = iw;                   iw += N_GRAPH + 1;
    int* bsum    = iw;                     iw += NBLK;

    hipMemsetAsync(deg, 0, 2 * N_NODES * sizeof(int), stream);
    hipMemsetAsync(bnslots, 0, (size_t)3 * BN_SLOTS * 512 * sizeof(float), stream);

    // weight fragment-swizzle to fp16 (once per layer)
    for (int l = 0; l < 3; ++l) {
        bs16_kernel<<<(FIN[l] * 256 + 255) / 256, 256, 0, stream>>>(W1[l], w1f[l], FIN[l]);
        bs16_kernel<<<(256 * 256 + 255) / 256, 256, 0, stream>>>(W2[l], w2f[l], 256);
    }

    // CSR build (hierarchical scan)
    count_deg_kernel<<<(N_EDGES + 255) / 256, 256, 0, stream>>>(ei, deg);
    block_sum_kernel<<<NBLK, 256, 0, stream>>>(deg, bsum);
    top_scan_kernel<<<1, 256, 0, stream>>>(bsum, NBLK);
    final_scan_kernel<<<NBLK, 256, 0, stream>>>(deg, bsum, row_ptr);
    fill_csr_kernel<<<(N_EDGES + 255) / 256, 256, 0, stream>>>(ei, row_ptr, fill, csr_src, csr_eid);

    segptr_kernel<<<(N_FRAG + 1 + 255) / 256, 256, 0, stream>>>(fb, N_FRAG, frag_ptr);
    segptr_kernel<<<(N_GRAPH + 1 + 255) / 256, 256, 0, stream>>>(gb, N_GRAPH, graph_ptr);

    edge_gather_kernel<<<(N_NODES + 31) / 32, 256, 0, stream>>>(ea, row_ptr, csr_eid, agg_e);

    const int nblk_mlp = (N_NODES + 31) / 32;    // 1563 blocks, 32 rows each
    // layer 0: Y0 = fp16(relu(x)), self = x (fp32)
    relu16_f32_kernel<<<(N_NODES * 128 / 4 + 255) / 256, 256, 0, stream>>>(x, ybuf);
    {
        float* slotsL = bnslots;
        fused_mlp_kernel<false, float, 4><<<nblk_mlp, 256, 0, stream>>>(
            x, ybuf, row_ptr, csr_src, agg_e, nullptr, nullptr,
            w1f[0], B1[0], w2f[0], B2[0], bufA, slotsL);
        bn_finalize_kernel<<<1, 256, 0, stream>>>(slotsL, G[0], BETA[0], bnss, bnss + 256);
    }
    // layer 1: Y = fp16(relu(BN0(bufA))), self = BN0(bufA)
    {
        float* slotsL = bnslots + (size_t)1 * BN_SLOTS * 512;
        const float* psc = bnss, * psh = bnss + 256;
        bnrelu16_kernel<<<(N_NODES * 256 / 8 + 255) / 256, 256, 0, stream>>>(bufA, psc, psh, ybuf);
        fused_mlp_kernel<true, _Float16, 8><<<nblk_mlp, 256, 0, stream>>>(
            bufA, ybuf, row_ptr, csr_src, agg_e, psc, psh,
            w1f[1], B1[1], w2f[1], B2[1], bufB, slotsL);
        bn_finalize_kernel<<<1, 256, 0, stream>>>(slotsL, G[1], BETA[1], bnss + 512, bnss + 768);
    }
    // layer 2: Y = fp16(relu(BN1(bufB))), self = BN1(bufB)
    {
        float* slotsL = bnslots + (size_t)2 * BN_SLOTS * 512;
        const float* psc = bnss + 512, * psh = bnss + 768;
        bnrelu16_kernel<<<(N_NODES * 256 / 8 + 255) / 256, 256, 0, stream>>>(bufB, psc, psh, ybuf);
        fused_mlp_kernel<true, _Float16, 8><<<nblk_mlp, 256, 0, stream>>>(
            bufB, ybuf, row_ptr, csr_src, agg_e, psc, psh,
            w1f[2], B1[2], w2f[2], B2[2], bufA, slotsL);
        bn_finalize_kernel<<<1, 256, 0, stream>>>(slotsL, G[2], BETA[2], bnss + 1024, bnss + 1280);
    }

    const float* fsc = bnss + 2 * 512;   // layer-2 BN scale/shift
    const float* fsh = fsc + 256;
    pool_seg_kernel<<<(N_FRAG + 3) / 4, 256, 0, stream>>>(bufA, frag_ptr, fsc, fsh,
                                                          (float*)d_out, N_FRAG);
    pool_seg_kernel<<<(N_GRAPH + 3) / 4, 256, 0, stream>>>(bufA, graph_ptr, fsc, fsh,
                                                           (float*)d_out + (size_t)N_FRAG * 256, N_GRAPH);
}